// Round 4
// baseline (1015.566 us; speedup 1.0000x reference)
//
#include <hip/hip_runtime.h>
#include <hip/hip_bf16.h>
#include <stdint.h>

typedef short short8 __attribute__((ext_vector_type(8)));
typedef float f32x4 __attribute__((ext_vector_type(4)));
typedef uint32_t u32x4 __attribute__((ext_vector_type(4)));

#define NTILES 6250   // 100000 / 16
#define GRID   512    // 2 blocks/CU

__device__ __forceinline__ uint32_t f32_to_bf16_rne(float f) {
    uint32_t u = __builtin_bit_cast(uint32_t, f);
    uint32_t r = u + 0x7FFFu + ((u >> 16) & 1u);
    return r >> 16;
}
// 1-op packed f32x2 -> bf16x2 (RNE), replaces 7-op manual pack
__device__ __forceinline__ uint32_t cvt_pk_bf16(float lo, float hi) {
    uint32_t r;
    asm("v_cvt_pk_bf16_f32 %0, %1, %2" : "=v"(r) : "v"(lo), "v"(hi));
    return r;
}

// ---------------------------------------------------------------------------
// Pre-kernel: Wt[l][o][i] = bf16(w_l[i][o])  (transposed so B-fragments are
// contiguous-in-i 16B loads). 4 * 128 * 128 bf16 = 128 KB in d_ws.
// ---------------------------------------------------------------------------
__global__ void conv_weights(const float* __restrict__ w0, const float* __restrict__ w1,
                             const float* __restrict__ w2, const float* __restrict__ w3,
                             uint16_t* __restrict__ wt) {
    int idx = blockIdx.x * 256 + threadIdx.x;   // 0 .. 65535
    int l = idx >> 14;
    int o = (idx >> 7) & 127;
    int i = idx & 127;
    const float* w = (l == 0) ? w0 : (l == 1) ? w1 : (l == 2) ? w2 : w3;
    wt[idx] = (uint16_t)f32_to_bf16_rne(w[i * 128 + o]);
}

// ---------------------------------------------------------------------------
// Main kernel: 512 persistent blocks x 512 thr (8 waves), SINGLE 64 KB LDS
// buffer -> 2 blocks/CU = 16 waves/CU (TLP doubles vs round 3).
// Per tile:  [lgkm(0); s_barrier]  write LDS <- v(t)  (vmcnt waits auto)
//            issue loads v <- t+GRID   (stay in flight across compute!)
//            [lgkm(0); s_barrier]  compute(t)+stores
// vmcnt is NEVER drained at a barrier; loads for t+1 stream during compute(t),
// and the co-resident second block fills stalls (m114 wave-level overlap).
// LDS x-tile layout (bf16, swizzled):
//   off(nn,c,i) = nn*4096 + ((c*256 + (i>>3)*16) ^ (((nn^c)&7)<<4)) + (i&7)*2
// MFMA 16x16x32 bf16: A row=lane&15(=nn), k=(lane>>4)*8+j(=i); B col=lane&15(=o);
// D col=lane&15(=o), row=(lane>>4)*4+reg(=nn).
// ---------------------------------------------------------------------------
__global__ void __launch_bounds__(512, 4)
isl_kernel(const float* __restrict__ x,
           const uint16_t* __restrict__ wt,
           float* __restrict__ out) {
    __shared__ uint8_t lds[65536];
    const int tid = threadIdx.x;

    // staging coords
    const int snn   = tid >> 5;        // 0..15 (row)
    const int sisub = (tid >> 2) & 7;  // i = sisub*16 + u
    const int scq   = tid & 3;         // c = scq*4 + cc

    // compute coords
    const int lane  = tid & 63;
    const int wid   = tid >> 6;     // 0..7 = this wave's o-tile
    const int row16 = lane & 15;
    const int kgrp  = lane >> 4;

    f32x4 v[16];
    int t = blockIdx.x;

    // ---- prologue: issue loads for first tile
    {
        const float* xb = x + (size_t)(t * 16 + snn) * 2048 + sisub * 256 + scq * 4;
        #pragma unroll
        for (int u = 0; u < 16; ++u)
            v[u] = *(const f32x4*)(xb + u * 16);
    }

    while (true) {
        // ---- barrier: all waves' LDS reads from previous compute are done
        asm volatile("s_waitcnt lgkmcnt(0)" ::: "memory");
        __builtin_amdgcn_s_barrier();

        // ---- write LDS from regs (compiler inserts vmcnt waits on v)
        {
            const uint32_t base = (uint32_t)snn * 4096;
            #pragma unroll
            for (int cc = 0; cc < 4; ++cc) {
                const int c = scq * 4 + cc;
                const uint32_t swz = ((uint32_t)((snn ^ c) & 7)) << 4;
                #pragma unroll
                for (int g = 0; g < 2; ++g) {   // i = sisub*16 + g*8 + 0..7
                    u32x4 p;
                    #pragma unroll
                    for (int q = 0; q < 4; ++q)
                        p[q] = cvt_pk_bf16(v[g * 8 + q * 2][cc], v[g * 8 + q * 2 + 1][cc]);
                    const uint32_t off = base +
                        (((uint32_t)(c * 256 + (sisub * 2 + g) * 16)) ^ swz);
                    *(u32x4*)(lds + off) = p;
                }
            }
        }

        // ---- issue next tile's loads (in flight across the barrier + compute)
        const int tn = t + GRID;
        const bool more = (tn < NTILES);
        if (more) {
            const float* xb = x + (size_t)(tn * 16 + snn) * 2048 + sisub * 256 + scq * 4;
            #pragma unroll
            for (int u = 0; u < 16; ++u)
                v[u] = *(const f32x4*)(xb + u * 16);
        }

        // ---- barrier: LDS writes visible; vmcnt NOT drained
        asm volatile("s_waitcnt lgkmcnt(0)" ::: "memory");
        __builtin_amdgcn_s_barrier();

        // ---- compute tile t from LDS
        {
            float* outb = out + (size_t)(t * 16) * 2048 + (size_t)(wid * 16 + row16) * 16;
            int lcur = -1;
            short8 b[4];
            #pragma unroll
            for (int ccq = 0; ccq < 4; ++ccq) {
                f32x4 acc4[4];
                #pragma unroll
                for (int c4 = 0; c4 < 4; ++c4) {
                    const int c = ccq * 4 + c4;
                    const int l = (c >= 1) + (c >= 4) + (c >= 9);
                    if (l != lcur) {   // constant-folded in the unrolled chain
                        lcur = l;
                        const uint16_t* wb = wt + (size_t)l * 16384 +
                                             (size_t)(wid * 16 + row16) * 128 + kgrp * 8;
                        #pragma unroll
                        for (int k = 0; k < 4; ++k)
                            b[k] = *(const short8*)(wb + k * 32);
                    }
                    const uint32_t swz = ((uint32_t)((row16 ^ c) & 7)) << 4;
                    f32x4 acc = {0.f, 0.f, 0.f, 0.f};
                    #pragma unroll
                    for (int k = 0; k < 4; ++k) {
                        const uint32_t off = (uint32_t)row16 * 4096 +
                            (((uint32_t)(c * 256 + (k * 4 + kgrp) * 16)) ^ swz);
                        short8 a = *(const short8*)(lds + off);
                        acc = __builtin_amdgcn_mfma_f32_16x16x32_bf16(a, b[k], acc, 0, 0, 0);
                    }
                    acc4[c4] = acc;
                }
                #pragma unroll
                for (int r = 0; r < 4; ++r) {
                    f32x4 o4 = {acc4[0][r], acc4[1][r], acc4[2][r], acc4[3][r]};
                    *(f32x4*)(outb + (size_t)(kgrp * 4 + r) * 2048 + ccq * 4) = o4;
                }
            }
        }

        if (!more) break;
        t = tn;
    }
}

extern "C" void kernel_launch(void* const* d_in, const int* in_sizes, int n_in,
                              void* d_out, int out_size, void* d_ws, size_t ws_size,
                              hipStream_t stream) {
    const float* x  = (const float*)d_in[0];
    const float* w0 = (const float*)d_in[1];
    const float* w1 = (const float*)d_in[2];
    const float* w2 = (const float*)d_in[3];
    const float* w3 = (const float*)d_in[4];
    uint16_t* wt = (uint16_t*)d_ws;          // 128 KB scratch
    float* out = (float*)d_out;

    conv_weights<<<256, 256, 0, stream>>>(w0, w1, w2, w3, wt);
    isl_kernel<<<GRID, 512, 0, stream>>>(x, wt, out);
}

// Round 5
// 470.730 us; speedup vs baseline: 2.1574x; 2.1574x over previous
//
#include <hip/hip_runtime.h>
#include <hip/hip_bf16.h>
#include <stdint.h>

typedef short short8 __attribute__((ext_vector_type(8)));
typedef float f32x4 __attribute__((ext_vector_type(4)));
typedef uint32_t u32x4 __attribute__((ext_vector_type(4)));

#define NTILES 6250   // 100000 / 16
#define GRID   512    // 2 blocks/CU

__device__ __forceinline__ uint32_t f32_to_bf16_rne(float f) {
    uint32_t u = __builtin_bit_cast(uint32_t, f);
    uint32_t r = u + 0x7FFFu + ((u >> 16) & 1u);
    return r >> 16;
}
// 1-op packed f32x2 -> bf16x2 (RNE)
__device__ __forceinline__ uint32_t cvt_pk_bf16(float lo, float hi) {
    uint32_t r;
    asm("v_cvt_pk_bf16_f32 %0, %1, %2" : "=v"(r) : "v"(lo), "v"(hi));
    return r;
}

// ---------------------------------------------------------------------------
// Pre-kernel: Wt[l][o][i] = bf16(w_l[i][o])  (transposed so B-fragments are
// contiguous-in-i 16B loads). 4 * 128 * 128 bf16 = 128 KB in d_ws.
// ---------------------------------------------------------------------------
__global__ void conv_weights(const float* __restrict__ w0, const float* __restrict__ w1,
                             const float* __restrict__ w2, const float* __restrict__ w3,
                             uint16_t* __restrict__ wt) {
    int idx = blockIdx.x * 256 + threadIdx.x;   // 0 .. 65535
    int l = idx >> 14;
    int o = (idx >> 7) & 127;
    int i = idx & 127;
    const float* w = (l == 0) ? w0 : (l == 1) ? w1 : (l == 2) ? w2 : w3;
    wt[idx] = (uint16_t)f32_to_bf16_rne(w[i * 128 + o]);
}

// ---------------------------------------------------------------------------
// Main kernel: 512 persistent blocks x 512 thr (8 waves), SINGLE 64 KB LDS
// buffer -> 2 blocks/CU = 16 waves/CU.
// NOTE on __launch_bounds__: on this toolchain arg2 empirically acts as
// blocks/CU (r3: (512,2)->VGPR cap 128 observed; r4: (512,4)->cap 64 observed,
// which spilled v[16] to scratch and doubled HBM traffic). Use (512,2).
// Per tile:  [lgkm(0); s_barrier]  write LDS <- v(t)  (vmcnt waits auto)
//            issue loads v <- t+GRID   (stay in flight across compute!)
//            [lgkm(0); s_barrier]  compute(t)+stores   (vmcnt NOT drained)
// LDS x-tile layout (bf16, swizzled):
//   off(nn,c,i) = nn*4096 + ((c*256 + (i>>3)*16) ^ (((nn^c)&7)<<4)) + (i&7)*2
// MFMA 16x16x32 bf16: A row=lane&15(=nn), k=(lane>>4)*8+j(=i); B col=lane&15(=o);
// D col=lane&15(=o), row=(lane>>4)*4+reg(=nn).
// ---------------------------------------------------------------------------
__global__ void __launch_bounds__(512, 2)
isl_kernel(const float* __restrict__ x,
           const uint16_t* __restrict__ wt,
           float* __restrict__ out) {
    __shared__ uint8_t lds[65536];
    const int tid = threadIdx.x;

    // staging coords
    const int snn   = tid >> 5;        // 0..15 (row)
    const int sisub = (tid >> 2) & 7;  // i = sisub*16 + u
    const int scq   = tid & 3;         // c = scq*4 + cc

    // compute coords
    const int lane  = tid & 63;
    const int wid   = tid >> 6;     // 0..7 = this wave's o-tile
    const int row16 = lane & 15;
    const int kgrp  = lane >> 4;

    f32x4 v[16];
    int t = blockIdx.x;

    // ---- prologue: issue loads for first tile
    {
        const float* xb = x + (size_t)(t * 16 + snn) * 2048 + sisub * 256 + scq * 4;
        #pragma unroll
        for (int u = 0; u < 16; ++u)
            v[u] = *(const f32x4*)(xb + u * 16);
    }

    while (true) {
        // ---- barrier: all waves' LDS reads from previous compute are done
        asm volatile("s_waitcnt lgkmcnt(0)" ::: "memory");
        __builtin_amdgcn_s_barrier();

        // ---- write LDS from regs (compiler inserts vmcnt waits on v)
        {
            const uint32_t base = (uint32_t)snn * 4096;
            #pragma unroll
            for (int cc = 0; cc < 4; ++cc) {
                const int c = scq * 4 + cc;
                const uint32_t swz = ((uint32_t)((snn ^ c) & 7)) << 4;
                #pragma unroll
                for (int g = 0; g < 2; ++g) {   // i = sisub*16 + g*8 + 0..7
                    u32x4 p;
                    #pragma unroll
                    for (int q = 0; q < 4; ++q)
                        p[q] = cvt_pk_bf16(v[g * 8 + q * 2][cc], v[g * 8 + q * 2 + 1][cc]);
                    const uint32_t off = base +
                        (((uint32_t)(c * 256 + (sisub * 2 + g) * 16)) ^ swz);
                    *(u32x4*)(lds + off) = p;
                }
            }
        }

        // ---- issue next tile's loads (in flight across the barrier + compute)
        const int tn = t + GRID;
        const bool more = (tn < NTILES);
        if (more) {
            const float* xb = x + (size_t)(tn * 16 + snn) * 2048 + sisub * 256 + scq * 4;
            #pragma unroll
            for (int u = 0; u < 16; ++u)
                v[u] = *(const f32x4*)(xb + u * 16);
        }

        // ---- barrier: LDS writes visible; vmcnt NOT drained
        asm volatile("s_waitcnt lgkmcnt(0)" ::: "memory");
        __builtin_amdgcn_s_barrier();

        // ---- compute tile t from LDS
        {
            float* outb = out + (size_t)(t * 16) * 2048 + (size_t)(wid * 16 + row16) * 16;
            int lcur = -1;
            short8 b[4];
            #pragma unroll
            for (int ccq = 0; ccq < 4; ++ccq) {
                f32x4 acc4[4];
                #pragma unroll
                for (int c4 = 0; c4 < 4; ++c4) {
                    const int c = ccq * 4 + c4;
                    const int l = (c >= 1) + (c >= 4) + (c >= 9);
                    if (l != lcur) {   // constant-folded in the unrolled chain
                        lcur = l;
                        const uint16_t* wb = wt + (size_t)l * 16384 +
                                             (size_t)(wid * 16 + row16) * 128 + kgrp * 8;
                        #pragma unroll
                        for (int k = 0; k < 4; ++k)
                            b[k] = *(const short8*)(wb + k * 32);
                    }
                    const uint32_t swz = ((uint32_t)((row16 ^ c) & 7)) << 4;
                    f32x4 acc = {0.f, 0.f, 0.f, 0.f};
                    #pragma unroll
                    for (int k = 0; k < 4; ++k) {
                        const uint32_t off = (uint32_t)row16 * 4096 +
                            (((uint32_t)(c * 256 + (k * 4 + kgrp) * 16)) ^ swz);
                        short8 a = *(const short8*)(lds + off);
                        acc = __builtin_amdgcn_mfma_f32_16x16x32_bf16(a, b[k], acc, 0, 0, 0);
                    }
                    acc4[c4] = acc;
                }
                #pragma unroll
                for (int r = 0; r < 4; ++r) {
                    f32x4 o4 = {acc4[0][r], acc4[1][r], acc4[2][r], acc4[3][r]};
                    *(f32x4*)(outb + (size_t)(kgrp * 4 + r) * 2048 + ccq * 4) = o4;
                }
            }
        }

        if (!more) break;
        t = tn;
    }
}

extern "C" void kernel_launch(void* const* d_in, const int* in_sizes, int n_in,
                              void* d_out, int out_size, void* d_ws, size_t ws_size,
                              hipStream_t stream) {
    const float* x  = (const float*)d_in[0];
    const float* w0 = (const float*)d_in[1];
    const float* w1 = (const float*)d_in[2];
    const float* w2 = (const float*)d_in[3];
    const float* w3 = (const float*)d_in[4];
    uint16_t* wt = (uint16_t*)d_ws;          // 128 KB scratch
    float* out = (float*)d_out;

    conv_weights<<<256, 256, 0, stream>>>(w0, w1, w2, w3, wt);
    isl_kernel<<<GRID, 512, 0, stream>>>(x, wt, out);
}